// Round 1
// baseline (48.604 us; speedup 1.0000x reference)
//
#include <hip/hip_runtime.h>

typedef __bf16 bf16x8 __attribute__((ext_vector_type(8)));
typedef float f32x4 __attribute__((ext_vector_type(4)));

constexpr int NP    = 256;    // n_patches
constexpr int DM    = 1024;   // d_model
constexpr int PL    = 64;     // patch_len
constexpr int PRED  = 720;
constexpr int P0    = 233;    // first patch contributing to last PRED outputs
constexpr int NPC   = 23;     // number of contributing patches (233..255)
constexpr int TMIN  = 7504;   // total_len - PRED = 8224 - 720
constexpr int TONE  = 8192;   // t >= TONE has count 1, else count 2 (in [TMIN,8224))

// Grid: x = patch (0..22), y = batch-tile (0..15, 32 batches each).
// Block: 128 threads = 2 waves; wave w computes a 16(batch) x 64(j) tile.
__global__ __launch_bounds__(128) void ph_gemm_fold(
    const float* __restrict__ x,     // [512][256][1024]
    const float* __restrict__ W,     // [64][1024]
    const float* __restrict__ bias,  // [64]
    float* __restrict__ out)         // [512][720], pre-zeroed
{
    const int p    = P0 + blockIdx.x;        // global patch index 233..255
    const int lane = threadIdx.x & 63;
    const int wave = threadIdx.x >> 6;       // 0..1
    const int r16  = lane & 15;
    const int kgrp = lane >> 4;              // 0..3

    const int bbase = blockIdx.y * 32 + wave * 16;   // first batch of wave tile

    // A-fragment source row: x[bbase + r16, p, :]
    const float* xrow = x + ((size_t)(bbase + r16) * NP + p) * DM;
    // B-fragment source rows: W[n*16 + r16, :]
    const float* wrow = W + (size_t)r16 * DM;

    f32x4 acc[4];
    #pragma unroll
    for (int n = 0; n < 4; ++n) acc[n] = (f32x4){0.f, 0.f, 0.f, 0.f};

    for (int k0 = 0; k0 < DM; k0 += 32) {
        const int kk = k0 + kgrp * 8;

        // A fragment: 8 consecutive k of x row (fp32 -> bf16 RTNE via cast)
        const float4 a0 = *(const float4*)(xrow + kk);
        const float4 a1 = *(const float4*)(xrow + kk + 4);
        bf16x8 af;
        af[0] = (__bf16)a0.x; af[1] = (__bf16)a0.y;
        af[2] = (__bf16)a0.z; af[3] = (__bf16)a0.w;
        af[4] = (__bf16)a1.x; af[5] = (__bf16)a1.y;
        af[6] = (__bf16)a1.z; af[7] = (__bf16)a1.w;

        #pragma unroll
        for (int n = 0; n < 4; ++n) {
            const float* wr = wrow + (size_t)n * 16 * DM + kk;
            const float4 b0 = *(const float4*)(wr);
            const float4 b1 = *(const float4*)(wr + 4);
            bf16x8 bf;
            bf[0] = (__bf16)b0.x; bf[1] = (__bf16)b0.y;
            bf[2] = (__bf16)b0.z; bf[3] = (__bf16)b0.w;
            bf[4] = (__bf16)b1.x; bf[5] = (__bf16)b1.y;
            bf[6] = (__bf16)b1.z; bf[7] = (__bf16)b1.w;
            acc[n] = __builtin_amdgcn_mfma_f32_16x16x32_bf16(af, bf, acc[n], 0, 0, 0);
        }
    }

    // Epilogue: D layout (m89): col(j) = lane&15, row(batch) = (lane>>4)*4 + reg.
    // t = p*32 + j maps each (p,j) to a unique output column; <=2 patches per t
    // -> atomicAdd into pre-zeroed out, scaled by 1/count(t), bias folded in.
    #pragma unroll
    for (int n = 0; n < 4; ++n) {
        const int j = n * 16 + r16;
        const int t = p * 32 + j;
        if (t >= TMIN) {
            const float bi  = bias[j];
            const float inv = (t >= TONE) ? 1.0f : 0.5f;
            const int   o   = t - TMIN;
            #pragma unroll
            for (int r = 0; r < 4; ++r) {
                const int b_ = bbase + kgrp * 4 + r;
                atomicAdd(out + (size_t)b_ * PRED + o, (acc[n][r] + bi) * inv);
            }
        }
    }
}

extern "C" void kernel_launch(void* const* d_in, const int* in_sizes, int n_in,
                              void* d_out, int out_size, void* d_ws, size_t ws_size,
                              hipStream_t stream) {
    const float* x    = (const float*)d_in[0];
    const float* W    = (const float*)d_in[1];
    const float* bias = (const float*)d_in[2];
    float* out = (float*)d_out;

    // zero the output accumulator (harness poisons it; atomics need zeros)
    hipMemsetAsync(out, 0, (size_t)out_size * sizeof(float), stream);

    dim3 grid(NPC, 16, 1);   // 23 patches x 16 batch-tiles(32)
    dim3 block(128, 1, 1);
    ph_gemm_fold<<<grid, block, 0, stream>>>(x, W, bias, out);
}

// Round 2
// 38.619 us; speedup vs baseline: 1.2585x; 1.2585x over previous
//
#include <hip/hip_runtime.h>

typedef __bf16 bf16x8 __attribute__((ext_vector_type(8)));
typedef float f32x4 __attribute__((ext_vector_type(4)));

constexpr int NP    = 256;    // n_patches
constexpr int DM    = 1024;   // d_model
constexpr int PRED  = 720;
constexpr int P0    = 233;    // first patch contributing to last PRED outputs
constexpr int NPC   = 23;     // patches 233..255
constexpr int TMIN  = 7504;   // total_len - PRED
constexpr int TONE  = 8192;   // t >= TONE: count 1, else count 2
constexpr int KC    = 128;    // K-chunk per block
constexpr int NKC   = DM / KC; // 8 K-slices

// ---- W fp32 -> bf16 conversion (once per launch, into d_ws) ----
__global__ __launch_bounds__(256) void wconv(const float* __restrict__ W,
                                             __bf16* __restrict__ Wb) {
    const int i = (blockIdx.x * 256 + threadIdx.x) * 4;   // 64 blocks cover 65536
    const float4 v = *(const float4*)(W + i);
    __bf16 o[4] = {(__bf16)v.x, (__bf16)v.y, (__bf16)v.z, (__bf16)v.w};
    *(short4*)(Wb + i) = *(short4*)o;
}

// Grid: x = patch (23), y = batch-tile (16 x 32 batches), z = K-slice (8).
// Block: 128 threads = 2 waves; wave computes 16(batch) x 64(j), K = 128.
__global__ __launch_bounds__(128) void ph_gemm_fold(
    const float*  __restrict__ x,     // [512][256][1024] fp32
    const __bf16* __restrict__ Wb,    // [64][1024] bf16 (in ws)
    const float*  __restrict__ bias,  // [64]
    float* __restrict__ out)          // [512][720], pre-zeroed
{
    const int p    = P0 + blockIdx.x;
    const int kc   = blockIdx.z;
    const int lane = threadIdx.x & 63;
    const int wave = threadIdx.x >> 6;
    const int r16  = lane & 15;
    const int kgrp = lane >> 4;

    const int bbase = blockIdx.y * 32 + wave * 16;

    const float*  xrow = x  + ((size_t)(bbase + r16) * NP + p) * DM + kc * KC;
    const __bf16* wrow = Wb + (size_t)r16 * DM + kc * KC;

    f32x4 acc[4];
    #pragma unroll
    for (int n = 0; n < 4; ++n) acc[n] = (f32x4){0.f, 0.f, 0.f, 0.f};

    #pragma unroll
    for (int k0 = 0; k0 < KC; k0 += 32) {
        const int kk = k0 + kgrp * 8;

        const float4 a0 = *(const float4*)(xrow + kk);
        const float4 a1 = *(const float4*)(xrow + kk + 4);
        bf16x8 af;
        af[0] = (__bf16)a0.x; af[1] = (__bf16)a0.y;
        af[2] = (__bf16)a0.z; af[3] = (__bf16)a0.w;
        af[4] = (__bf16)a1.x; af[5] = (__bf16)a1.y;
        af[6] = (__bf16)a1.z; af[7] = (__bf16)a1.w;

        #pragma unroll
        for (int n = 0; n < 4; ++n) {
            const bf16x8 bf = *(const bf16x8*)(wrow + (size_t)n * 16 * DM + kk);
            acc[n] = __builtin_amdgcn_mfma_f32_16x16x32_bf16(af, bf, acc[n], 0, 0, 0);
        }
    }

    // D layout: col(j) = lane&15, row(batch) = (lane>>4)*4 + reg.
    #pragma unroll
    for (int n = 0; n < 4; ++n) {
        const int j = n * 16 + r16;
        const int t = p * 32 + j;
        if (t >= TMIN) {
            const float inv = (t >= TONE) ? 1.0f : 0.5f;
            const float add = (kc == 0) ? bias[j] * inv : 0.0f;
            const int   o   = t - TMIN;
            #pragma unroll
            for (int r = 0; r < 4; ++r) {
                const int b_ = bbase + kgrp * 4 + r;
                atomicAdd(out + (size_t)b_ * PRED + o, acc[n][r] * inv + add);
            }
        }
    }
}

extern "C" void kernel_launch(void* const* d_in, const int* in_sizes, int n_in,
                              void* d_out, int out_size, void* d_ws, size_t ws_size,
                              hipStream_t stream) {
    const float* x    = (const float*)d_in[0];
    const float* W    = (const float*)d_in[1];
    const float* bias = (const float*)d_in[2];
    float*  out = (float*)d_out;
    __bf16* Wb  = (__bf16*)d_ws;

    hipMemsetAsync(out, 0, (size_t)out_size * sizeof(float), stream);
    wconv<<<64, 256, 0, stream>>>(W, Wb);   // 64*256*4 = 65536 elems

    dim3 grid(NPC, 16, NKC);
    ph_gemm_fold<<<grid, dim3(128), 0, stream>>>(x, Wb, bias, out);
}

// Round 3
// 30.645 us; speedup vs baseline: 1.5861x; 1.2602x over previous
//
#include <hip/hip_runtime.h>

typedef __bf16 bf16x8 __attribute__((ext_vector_type(8)));
typedef float f32x4 __attribute__((ext_vector_type(4)));

constexpr int NP    = 256;    // n_patches
constexpr int DM    = 1024;   // d_model
constexpr int PRED  = 720;
constexpr int P0    = 233;    // first patch contributing to last PRED outputs
constexpr int NPC   = 23;     // patches 233..255
constexpr int TMIN  = 7504;   // total_len - PRED
constexpr int TONE  = 8192;   // t >= TONE: count 1, else count 2
constexpr int KC    = 128;    // K-chunk per wave (8 waves x 128 = 1024)

// ---- W fp32 -> bf16 conversion (once per launch, into d_ws) ----
__global__ __launch_bounds__(256) void wconv(const float* __restrict__ W,
                                             __bf16* __restrict__ Wb) {
    const int i = (blockIdx.x * 256 + threadIdx.x) * 4;   // 64 blocks cover 65536
    const float4 v = *(const float4*)(W + i);
    __bf16 o[4] = {(__bf16)v.x, (__bf16)v.y, (__bf16)v.z, (__bf16)v.w};
    *(short4*)(Wb + i) = *(short4*)o;
}

// Grid: x = patch (23), y = batch-tile (32 x 16 batches).
// Block: 512 threads = 8 waves; wave w computes the SAME 16(batch) x 64(j)
// tile over K-slice [w*128, (w+1)*128); partials reduced in LDS; one
// atomicAdd per z-element (2 contributions per output address).
__global__ __launch_bounds__(512) void ph_gemm_fold(
    const float*  __restrict__ x,     // [512][256][1024] fp32
    const __bf16* __restrict__ Wb,    // [64][1024] bf16 (in ws)
    const float*  __restrict__ bias,  // [64]
    float* __restrict__ out)          // [512][720], pre-zeroed
{
    const int p    = P0 + blockIdx.x;
    const int lane = threadIdx.x & 63;
    const int wave = threadIdx.x >> 6;       // 0..7 = K-slice
    const int r16  = lane & 15;
    const int kgrp = lane >> 4;

    const int bbase = blockIdx.y * 16;

    __shared__ float red[8][16][65];         // +1 pad: 2-way max on writes

    const float*  xrow = x  + ((size_t)(bbase + r16) * NP + p) * DM + wave * KC;
    const __bf16* wrow = Wb + (size_t)r16 * DM + wave * KC;

    f32x4 acc[4];
    #pragma unroll
    for (int n = 0; n < 4; ++n) acc[n] = (f32x4){0.f, 0.f, 0.f, 0.f};

    #pragma unroll
    for (int k0 = 0; k0 < KC; k0 += 32) {
        const int kk = k0 + kgrp * 8;

        const float4 a0 = *(const float4*)(xrow + kk);
        const float4 a1 = *(const float4*)(xrow + kk + 4);
        bf16x8 af;
        af[0] = (__bf16)a0.x; af[1] = (__bf16)a0.y;
        af[2] = (__bf16)a0.z; af[3] = (__bf16)a0.w;
        af[4] = (__bf16)a1.x; af[5] = (__bf16)a1.y;
        af[6] = (__bf16)a1.z; af[7] = (__bf16)a1.w;

        #pragma unroll
        for (int n = 0; n < 4; ++n) {
            const bf16x8 bf = *(const bf16x8*)(wrow + (size_t)n * 16 * DM + kk);
            acc[n] = __builtin_amdgcn_mfma_f32_16x16x32_bf16(af, bf, acc[n], 0, 0, 0);
        }
    }

    // D layout (m89): col(j) = lane&15 (+n*16), row(batch) = (lane>>4)*4 + reg.
    #pragma unroll
    for (int n = 0; n < 4; ++n)
        #pragma unroll
        for (int r = 0; r < 4; ++r)
            red[wave][kgrp * 4 + r][n * 16 + r16] = acc[n][r];

    __syncthreads();

    // Reduce 8 K-partials, fold-scale, single atomicAdd per z-element.
    #pragma unroll
    for (int e = threadIdx.x; e < 1024; e += 512) {
        const int r = e >> 6;
        const int j = e & 63;
        float s = 0.0f;
        #pragma unroll
        for (int w = 0; w < 8; ++w) s += red[w][r][j];

        const int t = p * 32 + j;
        if (t >= TMIN) {
            const float inv = (t >= TONE) ? 1.0f : 0.5f;
            atomicAdd(out + (size_t)(bbase + r) * PRED + (t - TMIN),
                      (s + bias[j]) * inv);
        }
    }
}

extern "C" void kernel_launch(void* const* d_in, const int* in_sizes, int n_in,
                              void* d_out, int out_size, void* d_ws, size_t ws_size,
                              hipStream_t stream) {
    const float* x    = (const float*)d_in[0];
    const float* W    = (const float*)d_in[1];
    const float* bias = (const float*)d_in[2];
    float*  out = (float*)d_out;
    __bf16* Wb  = (__bf16*)d_ws;

    hipMemsetAsync(out, 0, (size_t)out_size * sizeof(float), stream);
    wconv<<<64, 256, 0, stream>>>(W, Wb);

    dim3 grid(NPC, 32, 1);   // 23 patches x 32 batch-tiles(16)
    ph_gemm_fold<<<grid, dim3(512), 0, stream>>>(x, Wb, bias, out);
}